// Round 11
// baseline (202.189 us; speedup 1.0000x reference)
//
#include <hip/hip_runtime.h>
#include <hip/hip_fp16.h>

#define N_NODES 200000
#define N_EDGES 4000000
#define N_GRAPHS 512
#define D 20
#define OUT 5

#define BSH 6            // bucket shift: 64 nodes per bucket
#define BN 64            // nodes per bucket
#define NB 3125          // ceil(200000/64)
#define NBP 3128         // padded to multiple of 4
#define NBB 3129         // bucket_base entries
#define NC 80            // edge chunks (few, large: line-coalesced partition writes)
#define CHUNK 50000      // NC*CHUNK == N_EDGES
#define MAX_EB 1792      // max edges/bucket (mean 1280, +14 sigma)
#define GMAX 8           // max graphs spanned by one 64-node bucket (typ. <= 2)

// ---------- P1: per-chunk bucket histogram (LDS int atomics); block 0 zeros gsum ----------
__launch_bounds__(512)
__global__ void k_hist(const int* __restrict__ dst, int* __restrict__ hist_g,
                       float* __restrict__ gsum) {
    __shared__ int h[NBP];
    int t = threadIdx.x;
    if (blockIdx.x == 0) {
        for (int j = t; j < N_GRAPHS * D; j += 512) gsum[j] = 0.f;
    }
    for (int j = t; j < NBP; j += 512) h[j] = 0;
    __syncthreads();
    int base = blockIdx.x * CHUNK;
    for (int k = t; k < CHUNK; k += 512) atomicAdd(&h[dst[base + k] >> BSH], 1);
    __syncthreads();
    for (int j = t; j < NBP; j += 512) hist_g[blockIdx.x * NBP + j] = h[j];
}

// ---------- P2: exclusive scan of chunk-columns, 4 buckets per block (no fences) ----------
__launch_bounds__(512)
__global__ void k_scan_col(int* __restrict__ hist_g, int* __restrict__ tot_g) {
    __shared__ int4 s[512];
    int t = threadIdx.x;
    int b0 = blockIdx.x * 4;
    int4 v = make_int4(0, 0, 0, 0);
    if (t < NC) v = *(const int4*)&hist_g[t * NBP + b0];
    s[t] = v;
    __syncthreads();
    for (int off = 1; off < 512; off <<= 1) {
        int4 a = make_int4(0, 0, 0, 0);
        if (t >= off) a = s[t - off];
        __syncthreads();
        s[t].x += a.x; s[t].y += a.y; s[t].z += a.z; s[t].w += a.w;
        __syncthreads();
    }
    if (t < NC) {
        int4 ex = s[t];
        ex.x -= v.x; ex.y -= v.y; ex.z -= v.z; ex.w -= v.w;
        *(int4*)&hist_g[t * NBP + b0] = ex;
    }
    if (t == 511) *(int4*)&tot_g[b0] = s[511];
}

// ---------- P3: exclusive scan of bucket totals (1 block, 4 elems/thread, no fences) ----------
__launch_bounds__(1024)
__global__ void k_scan_tot(const int* __restrict__ tot_g, int* __restrict__ bucket_base) {
    __shared__ int ps[1024];
    int t = threadIdx.x;
    int base = t * 4;                        // 1024*4 = 4096 >= NBP
    int loc[4];
    int sum = 0;
    #pragma unroll
    for (int j = 0; j < 4; j++) {
        int idx = base + j;
        int x = (idx < NBP) ? tot_g[idx] : 0;
        loc[j] = sum;
        sum += x;
    }
    ps[t] = sum;
    __syncthreads();
    for (int off = 1; off < 1024; off <<= 1) {
        int a = (t >= off) ? ps[t - off] : 0;
        __syncthreads();
        ps[t] += a;
        __syncthreads();
    }
    int carry = (t > 0) ? ps[t - 1] : 0;
    #pragma unroll
    for (int j = 0; j < 4; j++) {
        int idx = base + j;
        if (idx < NBB) bucket_base[idx] = carry + loc[j];
    }
}

// ---------- P4: partition edges into bucket-contiguous ebuf (packed) ----------
__launch_bounds__(512)
__global__ void k_partition(const int* __restrict__ src, const int* __restrict__ dst,
                            const int* __restrict__ hist_g, const int* __restrict__ bucket_base,
                            int* __restrict__ ebuf) {
    __shared__ int cur[NBP];
    int t = threadIdx.x, c = blockIdx.x;
    for (int j = t; j < NBP; j += 512) cur[j] = hist_g[c * NBP + j] + bucket_base[j];
    __syncthreads();
    int base = c * CHUNK;
    for (int k = t; k < CHUNK; k += 512) {
        int d = dst[base + k];
        int sv = src[base + k];
        int b = d >> BSH;
        int pos = atomicAdd(&cur[b], 1);
        ebuf[pos] = (sv << BSH) | (d & (BN - 1));
    }
}

// ---------- P5: per-bucket degree -> offs; xh = f16(dinv * x), packed 40B rows ----------
__launch_bounds__(256)
__global__ void k_count_xh(const int* __restrict__ ebuf, const int* __restrict__ bucket_base,
                           const float4* __restrict__ x4, int* __restrict__ offs_g,
                           uint2* __restrict__ xh2) {
    __shared__ int cnt[BN];
    __shared__ int s[BN];
    __shared__ float sdi[BN];
    int b = blockIdx.x, t = threadIdx.x;
    int eb = bucket_base[b], ee = bucket_base[b + 1];
    if (t < BN) cnt[t] = 0;
    __syncthreads();
    for (int k = eb + t; k < ee; k += 256) atomicAdd(&cnt[ebuf[k] & (BN - 1)], 1);
    __syncthreads();
    int nbn = N_NODES - (b << BSH); if (nbn > BN) nbn = BN;
    int v = (t < BN) ? cnt[t] : 0;
    if (t < BN) s[t] = v;
    __syncthreads();
    for (int off = 1; off < BN; off <<= 1) {
        int a = 0;
        if (t < BN && t >= off) a = s[t - off];
        __syncthreads();
        if (t < BN) s[t] += a;
        __syncthreads();
    }
    if (t < nbn) {
        int node = (b << BSH) + t;
        offs_g[node] = eb + s[t] - v;
        sdi[t] = rsqrtf((float)(v + 1));
    }
    __syncthreads();
    int nw = nbn * 5;
    for (int j = t; j < nw; j += 256) {
        int vl = j / 5, q = j - vl * 5;
        int node = (b << BSH) + vl;
        float4 xv = x4[node * 5 + q];
        float di = sdi[vl];
        __half2 h0 = __float22half2_rn(make_float2(xv.x * di, xv.y * di));
        __half2 h1 = __float22half2_rn(make_float2(xv.z * di, xv.w * di));
        uint2 u;
        u.x = *(unsigned int*)&h0;
        u.y = *(unsigned int*)&h1;
        xh2[node * 5 + q] = u;
    }
}

// ---------- P6: node-parallel gather (8x unrolled MLP) + W1 matvec + relu + pool ----------
__launch_bounds__(256, 8)
__global__ void k_gather_fused(const int* __restrict__ ebuf, const int* __restrict__ bucket_base,
                               const int* __restrict__ offs_g, const uint2* __restrict__ xh2,
                               const int* __restrict__ batch, const float* __restrict__ W1,
                               const float* __restrict__ b1, float* __restrict__ gsum) {
    __shared__ int loff[BN + 1];
    __shared__ int cur[BN];
    __shared__ int lcsr[MAX_EB];
    __shared__ float w[D * D];
    __shared__ float wb[D];
    __shared__ float sagg[BN][21];
    __shared__ float lgsum[GMAX][D];
    int b = blockIdx.x, t = threadIdx.x;
    int eb = bucket_base[b], ee = bucket_base[b + 1];
    int n = ee - eb;
    int nbn = N_NODES - (b << BSH); if (nbn > BN) nbn = BN;

    for (int j = t; j < D * D; j += 256) w[j] = W1[j];
    if (t < D) wb[t] = b1[t];
    if (t < GMAX * D) ((float*)lgsum)[t] = 0.f;
    if (t < nbn) {
        int o = offs_g[(b << BSH) + t] - eb;
        loff[t] = o;
        cur[t] = o;
    }
    if (t == 0) loff[nbn] = n;
    __syncthreads();

    // build bucket CSR in LDS
    for (int k = t; k < n; k += 256) {
        int p = ebuf[eb + k];
        int pos = atomicAdd(&cur[p & (BN - 1)], 1);
        if (pos < MAX_EB) lcsr[pos] = p >> BSH;
    }
    __syncthreads();

    // gather: sagg[vl] = xh[v] + sum over in-neighbors xh[s], 8x/4x/1x unrolled
    int nw = nbn * 5;
    for (int j = t; j < nw; j += 256) {
        int vl = j / 5, q = j - vl * 5;
        int node = (b << BSH) + vl;
        uint2 u = xh2[node * 5 + q];
        float2 a0 = __half22float2(*(__half2*)&u.x);
        float2 a1 = __half22float2(*(__half2*)&u.y);
        float accx = a0.x, accy = a0.y, accz = a1.x, accw = a1.y;
        float bccx = 0.f, bccy = 0.f, bccz = 0.f, bccw = 0.f;
        int lo = loff[vl], hi = loff[vl + 1];
        if (hi > MAX_EB) hi = MAX_EB;
        if (lo > MAX_EB) lo = MAX_EB;
        int k = lo;
        for (; k + 8 <= hi; k += 8) {
            int s0 = lcsr[k],     s1 = lcsr[k + 1], s2 = lcsr[k + 2], s3 = lcsr[k + 3];
            int s4 = lcsr[k + 4], s5 = lcsr[k + 5], s6 = lcsr[k + 6], s7 = lcsr[k + 7];
            uint2 m0 = xh2[s0 * 5 + q];
            uint2 m1 = xh2[s1 * 5 + q];
            uint2 m2 = xh2[s2 * 5 + q];
            uint2 m3 = xh2[s3 * 5 + q];
            uint2 m4 = xh2[s4 * 5 + q];
            uint2 m5 = xh2[s5 * 5 + q];
            uint2 m6 = xh2[s6 * 5 + q];
            uint2 m7 = xh2[s7 * 5 + q];
            float2 p0 = __half22float2(*(__half2*)&m0.x);
            float2 p1 = __half22float2(*(__half2*)&m0.y);
            float2 q0 = __half22float2(*(__half2*)&m1.x);
            float2 q1 = __half22float2(*(__half2*)&m1.y);
            float2 r0 = __half22float2(*(__half2*)&m2.x);
            float2 r1 = __half22float2(*(__half2*)&m2.y);
            float2 t0 = __half22float2(*(__half2*)&m3.x);
            float2 t1 = __half22float2(*(__half2*)&m3.y);
            accx += p0.x + q0.x; accy += p0.y + q0.y;
            accz += p1.x + q1.x; accw += p1.y + q1.y;
            bccx += r0.x + t0.x; bccy += r0.y + t0.y;
            bccz += r1.x + t1.x; bccw += r1.y + t1.y;
            float2 p2 = __half22float2(*(__half2*)&m4.x);
            float2 p3 = __half22float2(*(__half2*)&m4.y);
            float2 q2 = __half22float2(*(__half2*)&m5.x);
            float2 q3 = __half22float2(*(__half2*)&m5.y);
            float2 r2 = __half22float2(*(__half2*)&m6.x);
            float2 r3 = __half22float2(*(__half2*)&m6.y);
            float2 t2 = __half22float2(*(__half2*)&m7.x);
            float2 t3 = __half22float2(*(__half2*)&m7.y);
            accx += p2.x + q2.x; accy += p2.y + q2.y;
            accz += p3.x + q3.x; accw += p3.y + q3.y;
            bccx += r2.x + t2.x; bccy += r2.y + t2.y;
            bccz += r3.x + t3.x; bccw += r3.y + t3.y;
        }
        for (; k + 4 <= hi; k += 4) {
            int s0 = lcsr[k], s1 = lcsr[k + 1], s2 = lcsr[k + 2], s3 = lcsr[k + 3];
            uint2 m0 = xh2[s0 * 5 + q];
            uint2 m1 = xh2[s1 * 5 + q];
            uint2 m2 = xh2[s2 * 5 + q];
            uint2 m3 = xh2[s3 * 5 + q];
            float2 p0 = __half22float2(*(__half2*)&m0.x);
            float2 p1 = __half22float2(*(__half2*)&m0.y);
            float2 q0 = __half22float2(*(__half2*)&m1.x);
            float2 q1 = __half22float2(*(__half2*)&m1.y);
            float2 r0 = __half22float2(*(__half2*)&m2.x);
            float2 r1 = __half22float2(*(__half2*)&m2.y);
            float2 t0 = __half22float2(*(__half2*)&m3.x);
            float2 t1 = __half22float2(*(__half2*)&m3.y);
            accx += p0.x + q0.x; accy += p0.y + q0.y;
            accz += p1.x + q1.x; accw += p1.y + q1.y;
            bccx += r0.x + t0.x; bccy += r0.y + t0.y;
            bccz += r1.x + t1.x; bccw += r1.y + t1.y;
        }
        for (; k < hi; k++) {
            int sv = lcsr[k];
            uint2 m = xh2[sv * 5 + q];
            float2 m0 = __half22float2(*(__half2*)&m.x);
            float2 m1 = __half22float2(*(__half2*)&m.y);
            accx += m0.x; accy += m0.y; accz += m1.x; accw += m1.y;
        }
        sagg[vl][q * 4 + 0] = accx + bccx;
        sagg[vl][q * 4 + 1] = accy + bccy;
        sagg[vl][q * 4 + 2] = accz + bccz;
        sagg[vl][q * 4 + 3] = accw + bccw;
    }
    __syncthreads();

    int g0 = batch[b << BSH];
    int glast = batch[(b << BSH) + nbn - 1];
    int gcnt = glast - g0 + 1;

    if (t < nbn) {
        int node = (b << BSH) + t;
        float di = rsqrtf((float)(loff[t + 1] - loff[t] + 1));
        int gi = batch[node] - g0;
        float pre[D];
        #pragma unroll
        for (int d = 0; d < D; d++) pre[d] = sagg[t][d];
        int t20 = t % D;
        bool fits = (gcnt <= GMAX);
        for (int jj = 0; jj < D; jj++) {
            int o = t20 + jj; if (o >= D) o -= D;
            float h = 0.f;
            #pragma unroll
            for (int d = 0; d < D; d++) h = fmaf(pre[d], w[d * D + o], h);
            h = fmaf(h, di, wb[o]);
            h = fmaxf(h, 0.f);
            if (fits) atomicAdd(&lgsum[gi][o], h);
            else atomicAdd(&gsum[(g0 + gi) * D + o], h);  // safety path
        }
    }
    __syncthreads();
    if (gcnt <= GMAX && t < gcnt * D) {
        atomicAdd(&gsum[(g0 + t / D) * D + (t % D)], lgsum[t / D][t % D]);
    }
}

// ---------- P7: head: mean -> W_out -> softmax ----------
__launch_bounds__(64)
__global__ void k_head(const float* __restrict__ gsum, const int* __restrict__ batch,
                       const float* __restrict__ W_out, const float* __restrict__ b_out,
                       float* __restrict__ out) {
    __shared__ float wo[D * OUT];
    __shared__ float bo[OUT];
    int t = threadIdx.x;
    for (int j = t; j < D * OUT; j += 64) wo[j] = W_out[j];
    if (t < OUT) bo[t] = b_out[t];
    __syncthreads();
    int g = blockIdx.x * 64 + t;
    if (g >= N_GRAPHS) return;
    auto lb = [&](int key) {
        int lo = 0, hi = N_NODES;
        while (lo < hi) { int mid = (lo + hi) >> 1; if (batch[mid] < key) lo = mid + 1; else hi = mid; }
        return lo;
    };
    int cnt = lb(g + 1) - lb(g);
    float inv = 1.0f / fmaxf((float)cnt, 1.0f);
    float logits[OUT];
    #pragma unroll
    for (int o = 0; o < OUT; o++) logits[o] = bo[o];
    #pragma unroll
    for (int d = 0; d < D; d++) {
        float p = gsum[g * D + d] * inv;
        #pragma unroll
        for (int o = 0; o < OUT; o++) logits[o] = fmaf(p, wo[d * OUT + o], logits[o]);
    }
    float m = logits[0];
    #pragma unroll
    for (int o = 1; o < OUT; o++) m = fmaxf(m, logits[o]);
    float ex[OUT], sum = 0.f;
    #pragma unroll
    for (int o = 0; o < OUT; o++) { ex[o] = __expf(logits[o] - m); sum += ex[o]; }
    float isum = 1.0f / sum;
    #pragma unroll
    for (int o = 0; o < OUT; o++) out[g * OUT + o] = ex[o] * isum;
}

extern "C" void kernel_launch(void* const* d_in, const int* in_sizes, int n_in,
                              void* d_out, int out_size, void* d_ws, size_t ws_size,
                              hipStream_t stream) {
    const float* x     = (const float*)d_in[0];
    const int*   edge  = (const int*)d_in[1];
    const int*   batch = (const int*)d_in[2];
    const float* W1    = (const float*)d_in[3];
    const float* b1    = (const float*)d_in[4];
    const float* W_out = (const float*)d_in[5];
    const float* b_out = (const float*)d_in[6];
    float* out = (float*)d_out;

    const int* src = edge;
    const int* dst = edge + N_EDGES;
    char* ws = (char*)d_ws;

    // workspace layout (bytes):
    int*   hist_g      = (int*)(ws);                  // 80*3128*4 = 1,000,960
    int*   tot_g       = (int*)(ws + 6256000);        // 3128*4
    int*   bucket_base = (int*)(ws + 6268544);        // 3129*4
    float* gsum        = (float*)(ws + 6281152);      // 512*20*4
    int*   offs_g      = (int*)(ws + 6322176);        // 800,000
    uint2* xh2         = (uint2*)(ws + 7122176);      // 8,000,000 (packed f16 rows, 40 B/node)
    int*   ebuf        = (int*)(ws + 15122176);       // 16,000,000

    k_hist<<<NC, 512, 0, stream>>>(dst, hist_g, gsum);
    k_scan_col<<<NBP / 4, 512, 0, stream>>>(hist_g, tot_g);
    k_scan_tot<<<1, 1024, 0, stream>>>(tot_g, bucket_base);
    k_partition<<<NC, 512, 0, stream>>>(src, dst, hist_g, bucket_base, ebuf);
    k_count_xh<<<NB, 256, 0, stream>>>(ebuf, bucket_base, (const float4*)x, offs_g, xh2);
    k_gather_fused<<<NB, 256, 0, stream>>>(ebuf, bucket_base, offs_g, xh2, batch, W1, b1, gsum);
    k_head<<<(N_GRAPHS + 63) / 64, 64, 0, stream>>>(gsum, batch, W_out, b_out, out);
}

// Round 12
// 174.145 us; speedup vs baseline: 1.1610x; 1.1610x over previous
//
#include <hip/hip_runtime.h>
#include <hip/hip_fp16.h>

#define N_NODES 200000
#define N_EDGES 4000000
#define N_GRAPHS 512
#define D 20
#define OUT 5

#define BSH 6            // bucket shift: 64 nodes per bucket
#define BN 64            // nodes per bucket
#define NB 3125          // ceil(200000/64)
#define NBP 3128         // padded to multiple of 4
#define NBB 3129         // bucket_base entries
#define NC 500           // edge chunks
#define CHUNK 8000       // NC*CHUNK == N_EDGES
#define MAX_EB 1792      // max edges/bucket (mean 1280, +14 sigma)
#define GMAX 8           // max graphs spanned by one 64-node bucket (typ. <= 2)

// ---------- P1: per-chunk bucket histogram (LDS int atomics); block 0 zeros gsum ----------
__launch_bounds__(1024)
__global__ void k_hist(const int* __restrict__ dst, int* __restrict__ hist_g,
                       float* __restrict__ gsum) {
    __shared__ int h[NBP];
    int t = threadIdx.x;
    if (blockIdx.x == 0) {
        for (int j = t; j < N_GRAPHS * D; j += 1024) gsum[j] = 0.f;
    }
    for (int j = t; j < NBP; j += 1024) h[j] = 0;
    __syncthreads();
    int base = blockIdx.x * CHUNK;
    for (int k = t; k < CHUNK; k += 1024) atomicAdd(&h[dst[base + k] >> BSH], 1);
    __syncthreads();
    for (int j = t; j < NBP; j += 1024) hist_g[blockIdx.x * NBP + j] = h[j];
}

// ---------- P2: exclusive scan of chunk-columns, 4 buckets per block (no fences) ----------
__launch_bounds__(512)
__global__ void k_scan_col(int* __restrict__ hist_g, int* __restrict__ tot_g) {
    __shared__ int4 s[512];
    int t = threadIdx.x;
    int b0 = blockIdx.x * 4;
    int4 v = make_int4(0, 0, 0, 0);
    if (t < NC) v = *(const int4*)&hist_g[t * NBP + b0];
    s[t] = v;
    __syncthreads();
    for (int off = 1; off < 512; off <<= 1) {
        int4 a = make_int4(0, 0, 0, 0);
        if (t >= off) a = s[t - off];
        __syncthreads();
        s[t].x += a.x; s[t].y += a.y; s[t].z += a.z; s[t].w += a.w;
        __syncthreads();
    }
    if (t < NC) {
        int4 ex = s[t];
        ex.x -= v.x; ex.y -= v.y; ex.z -= v.z; ex.w -= v.w;
        *(int4*)&hist_g[t * NBP + b0] = ex;
    }
    if (t == 511) *(int4*)&tot_g[b0] = s[511];
}

// ---------- P3: exclusive scan of bucket totals (1 block, 4 elems/thread, no fences) ----------
__launch_bounds__(1024)
__global__ void k_scan_tot(const int* __restrict__ tot_g, int* __restrict__ bucket_base) {
    __shared__ int ps[1024];
    int t = threadIdx.x;
    int base = t * 4;                        // 1024*4 = 4096 >= NBP
    int loc[4];
    int sum = 0;
    #pragma unroll
    for (int j = 0; j < 4; j++) {
        int idx = base + j;
        int x = (idx < NBP) ? tot_g[idx] : 0;
        loc[j] = sum;
        sum += x;
    }
    ps[t] = sum;
    __syncthreads();
    for (int off = 1; off < 1024; off <<= 1) {
        int a = (t >= off) ? ps[t - off] : 0;
        __syncthreads();
        ps[t] += a;
        __syncthreads();
    }
    int carry = (t > 0) ? ps[t - 1] : 0;
    #pragma unroll
    for (int j = 0; j < 4; j++) {
        int idx = base + j;
        if (idx < NBB) bucket_base[idx] = carry + loc[j];
    }
}

// ---------- P4: partition edges into bucket-contiguous ebuf (packed) ----------
__launch_bounds__(1024)
__global__ void k_partition(const int* __restrict__ src, const int* __restrict__ dst,
                            const int* __restrict__ hist_g, const int* __restrict__ bucket_base,
                            int* __restrict__ ebuf) {
    __shared__ int cur[NBP];
    int t = threadIdx.x, c = blockIdx.x;
    for (int j = t; j < NBP; j += 1024) cur[j] = hist_g[c * NBP + j] + bucket_base[j];
    __syncthreads();
    int base = c * CHUNK;
    for (int k = t; k < CHUNK; k += 1024) {
        int d = dst[base + k];
        int sv = src[base + k];
        int b = d >> BSH;
        int pos = atomicAdd(&cur[b], 1);
        ebuf[pos] = (sv << BSH) | (d & (BN - 1));
    }
}

// ---------- P5: per-bucket degree -> offs; xh = f16(dinv * x), packed 40B rows ----------
__launch_bounds__(256)
__global__ void k_count_xh(const int* __restrict__ ebuf, const int* __restrict__ bucket_base,
                           const float4* __restrict__ x4, int* __restrict__ offs_g,
                           uint2* __restrict__ xh2) {
    __shared__ int cnt[BN];
    __shared__ int s[BN];
    __shared__ float sdi[BN];
    int b = blockIdx.x, t = threadIdx.x;
    int eb = bucket_base[b], ee = bucket_base[b + 1];
    if (t < BN) cnt[t] = 0;
    __syncthreads();
    for (int k = eb + t; k < ee; k += 256) atomicAdd(&cnt[ebuf[k] & (BN - 1)], 1);
    __syncthreads();
    int nbn = N_NODES - (b << BSH); if (nbn > BN) nbn = BN;
    int v = (t < BN) ? cnt[t] : 0;
    if (t < BN) s[t] = v;
    __syncthreads();
    for (int off = 1; off < BN; off <<= 1) {
        int a = 0;
        if (t < BN && t >= off) a = s[t - off];
        __syncthreads();
        if (t < BN) s[t] += a;
        __syncthreads();
    }
    if (t < nbn) {
        int node = (b << BSH) + t;
        offs_g[node] = eb + s[t] - v;
        sdi[t] = rsqrtf((float)(v + 1));
    }
    __syncthreads();
    int nw = nbn * 5;
    for (int j = t; j < nw; j += 256) {
        int vl = j / 5, q = j - vl * 5;
        int node = (b << BSH) + vl;
        float4 xv = x4[node * 5 + q];
        float di = sdi[vl];
        __half2 h0 = __float22half2_rn(make_float2(xv.x * di, xv.y * di));
        __half2 h1 = __float22half2_rn(make_float2(xv.z * di, xv.w * di));
        uint2 u;
        u.x = *(unsigned int*)&h0;
        u.y = *(unsigned int*)&h1;
        xh2[node * 5 + q] = u;
    }
}

// ---------- P6: node-parallel gather (8x unrolled MLP) + W1 matvec + relu + pool ----------
__launch_bounds__(256, 8)
__global__ void k_gather_fused(const int* __restrict__ ebuf, const int* __restrict__ bucket_base,
                               const int* __restrict__ offs_g, const uint2* __restrict__ xh2,
                               const int* __restrict__ batch, const float* __restrict__ W1,
                               const float* __restrict__ b1, float* __restrict__ gsum) {
    __shared__ int loff[BN + 1];
    __shared__ int cur[BN];
    __shared__ int lcsr[MAX_EB];
    __shared__ float w[D * D];
    __shared__ float wb[D];
    __shared__ float sagg[BN][21];
    __shared__ float lgsum[GMAX][D];
    int b = blockIdx.x, t = threadIdx.x;
    int eb = bucket_base[b], ee = bucket_base[b + 1];
    int n = ee - eb;
    int nbn = N_NODES - (b << BSH); if (nbn > BN) nbn = BN;

    for (int j = t; j < D * D; j += 256) w[j] = W1[j];
    if (t < D) wb[t] = b1[t];
    if (t < GMAX * D) ((float*)lgsum)[t] = 0.f;
    if (t < nbn) {
        int o = offs_g[(b << BSH) + t] - eb;
        loff[t] = o;
        cur[t] = o;
    }
    if (t == 0) loff[nbn] = n;
    __syncthreads();

    // build bucket CSR in LDS
    for (int k = t; k < n; k += 256) {
        int p = ebuf[eb + k];
        int pos = atomicAdd(&cur[p & (BN - 1)], 1);
        if (pos < MAX_EB) lcsr[pos] = p >> BSH;
    }
    __syncthreads();

    // gather: sagg[vl] = xh[v] + sum over in-neighbors xh[s], 8x/4x/1x unrolled
    int nw = nbn * 5;
    for (int j = t; j < nw; j += 256) {
        int vl = j / 5, q = j - vl * 5;
        int node = (b << BSH) + vl;
        uint2 u = xh2[node * 5 + q];
        float2 a0 = __half22float2(*(__half2*)&u.x);
        float2 a1 = __half22float2(*(__half2*)&u.y);
        float accx = a0.x, accy = a0.y, accz = a1.x, accw = a1.y;
        float bccx = 0.f, bccy = 0.f, bccz = 0.f, bccw = 0.f;
        int lo = loff[vl], hi = loff[vl + 1];
        if (hi > MAX_EB) hi = MAX_EB;
        if (lo > MAX_EB) lo = MAX_EB;
        int k = lo;
        for (; k + 8 <= hi; k += 8) {
            int s0 = lcsr[k],     s1 = lcsr[k + 1], s2 = lcsr[k + 2], s3 = lcsr[k + 3];
            int s4 = lcsr[k + 4], s5 = lcsr[k + 5], s6 = lcsr[k + 6], s7 = lcsr[k + 7];
            uint2 m0 = xh2[s0 * 5 + q];
            uint2 m1 = xh2[s1 * 5 + q];
            uint2 m2 = xh2[s2 * 5 + q];
            uint2 m3 = xh2[s3 * 5 + q];
            uint2 m4 = xh2[s4 * 5 + q];
            uint2 m5 = xh2[s5 * 5 + q];
            uint2 m6 = xh2[s6 * 5 + q];
            uint2 m7 = xh2[s7 * 5 + q];
            float2 p0 = __half22float2(*(__half2*)&m0.x);
            float2 p1 = __half22float2(*(__half2*)&m0.y);
            float2 q0 = __half22float2(*(__half2*)&m1.x);
            float2 q1 = __half22float2(*(__half2*)&m1.y);
            float2 r0 = __half22float2(*(__half2*)&m2.x);
            float2 r1 = __half22float2(*(__half2*)&m2.y);
            float2 t0 = __half22float2(*(__half2*)&m3.x);
            float2 t1 = __half22float2(*(__half2*)&m3.y);
            accx += p0.x + q0.x; accy += p0.y + q0.y;
            accz += p1.x + q1.x; accw += p1.y + q1.y;
            bccx += r0.x + t0.x; bccy += r0.y + t0.y;
            bccz += r1.x + t1.x; bccw += r1.y + t1.y;
            float2 p2 = __half22float2(*(__half2*)&m4.x);
            float2 p3 = __half22float2(*(__half2*)&m4.y);
            float2 q2 = __half22float2(*(__half2*)&m5.x);
            float2 q3 = __half22float2(*(__half2*)&m5.y);
            float2 r2 = __half22float2(*(__half2*)&m6.x);
            float2 r3 = __half22float2(*(__half2*)&m6.y);
            float2 t2 = __half22float2(*(__half2*)&m7.x);
            float2 t3 = __half22float2(*(__half2*)&m7.y);
            accx += p2.x + q2.x; accy += p2.y + q2.y;
            accz += p3.x + q3.x; accw += p3.y + q3.y;
            bccx += r2.x + t2.x; bccy += r2.y + t2.y;
            bccz += r3.x + t3.x; bccw += r3.y + t3.y;
        }
        for (; k + 4 <= hi; k += 4) {
            int s0 = lcsr[k], s1 = lcsr[k + 1], s2 = lcsr[k + 2], s3 = lcsr[k + 3];
            uint2 m0 = xh2[s0 * 5 + q];
            uint2 m1 = xh2[s1 * 5 + q];
            uint2 m2 = xh2[s2 * 5 + q];
            uint2 m3 = xh2[s3 * 5 + q];
            float2 p0 = __half22float2(*(__half2*)&m0.x);
            float2 p1 = __half22float2(*(__half2*)&m0.y);
            float2 q0 = __half22float2(*(__half2*)&m1.x);
            float2 q1 = __half22float2(*(__half2*)&m1.y);
            float2 r0 = __half22float2(*(__half2*)&m2.x);
            float2 r1 = __half22float2(*(__half2*)&m2.y);
            float2 t0 = __half22float2(*(__half2*)&m3.x);
            float2 t1 = __half22float2(*(__half2*)&m3.y);
            accx += p0.x + q0.x; accy += p0.y + q0.y;
            accz += p1.x + q1.x; accw += p1.y + q1.y;
            bccx += r0.x + t0.x; bccy += r0.y + t0.y;
            bccz += r1.x + t1.x; bccw += r1.y + t1.y;
        }
        for (; k < hi; k++) {
            int sv = lcsr[k];
            uint2 m = xh2[sv * 5 + q];
            float2 m0 = __half22float2(*(__half2*)&m.x);
            float2 m1 = __half22float2(*(__half2*)&m.y);
            accx += m0.x; accy += m0.y; accz += m1.x; accw += m1.y;
        }
        sagg[vl][q * 4 + 0] = accx + bccx;
        sagg[vl][q * 4 + 1] = accy + bccy;
        sagg[vl][q * 4 + 2] = accz + bccz;
        sagg[vl][q * 4 + 3] = accw + bccw;
    }
    __syncthreads();

    int g0 = batch[b << BSH];
    int glast = batch[(b << BSH) + nbn - 1];
    int gcnt = glast - g0 + 1;

    if (t < nbn) {
        int node = (b << BSH) + t;
        float di = rsqrtf((float)(loff[t + 1] - loff[t] + 1));
        int gi = batch[node] - g0;
        float pre[D];
        #pragma unroll
        for (int d = 0; d < D; d++) pre[d] = sagg[t][d];
        int t20 = t % D;
        bool fits = (gcnt <= GMAX);
        for (int jj = 0; jj < D; jj++) {
            int o = t20 + jj; if (o >= D) o -= D;
            float h = 0.f;
            #pragma unroll
            for (int d = 0; d < D; d++) h = fmaf(pre[d], w[d * D + o], h);
            h = fmaf(h, di, wb[o]);
            h = fmaxf(h, 0.f);
            if (fits) atomicAdd(&lgsum[gi][o], h);
            else atomicAdd(&gsum[(g0 + gi) * D + o], h);  // safety path
        }
    }
    __syncthreads();
    if (gcnt <= GMAX && t < gcnt * D) {
        atomicAdd(&gsum[(g0 + t / D) * D + (t % D)], lgsum[t / D][t % D]);
    }
}

// ---------- P7: head: mean -> W_out -> softmax ----------
__launch_bounds__(64)
__global__ void k_head(const float* __restrict__ gsum, const int* __restrict__ batch,
                       const float* __restrict__ W_out, const float* __restrict__ b_out,
                       float* __restrict__ out) {
    __shared__ float wo[D * OUT];
    __shared__ float bo[OUT];
    int t = threadIdx.x;
    for (int j = t; j < D * OUT; j += 64) wo[j] = W_out[j];
    if (t < OUT) bo[t] = b_out[t];
    __syncthreads();
    int g = blockIdx.x * 64 + t;
    if (g >= N_GRAPHS) return;
    auto lb = [&](int key) {
        int lo = 0, hi = N_NODES;
        while (lo < hi) { int mid = (lo + hi) >> 1; if (batch[mid] < key) lo = mid + 1; else hi = mid; }
        return lo;
    };
    int cnt = lb(g + 1) - lb(g);
    float inv = 1.0f / fmaxf((float)cnt, 1.0f);
    float logits[OUT];
    #pragma unroll
    for (int o = 0; o < OUT; o++) logits[o] = bo[o];
    #pragma unroll
    for (int d = 0; d < D; d++) {
        float p = gsum[g * D + d] * inv;
        #pragma unroll
        for (int o = 0; o < OUT; o++) logits[o] = fmaf(p, wo[d * OUT + o], logits[o]);
    }
    float m = logits[0];
    #pragma unroll
    for (int o = 1; o < OUT; o++) m = fmaxf(m, logits[o]);
    float ex[OUT], sum = 0.f;
    #pragma unroll
    for (int o = 0; o < OUT; o++) { ex[o] = __expf(logits[o] - m); sum += ex[o]; }
    float isum = 1.0f / sum;
    #pragma unroll
    for (int o = 0; o < OUT; o++) out[g * OUT + o] = ex[o] * isum;
}

extern "C" void kernel_launch(void* const* d_in, const int* in_sizes, int n_in,
                              void* d_out, int out_size, void* d_ws, size_t ws_size,
                              hipStream_t stream) {
    const float* x     = (const float*)d_in[0];
    const int*   edge  = (const int*)d_in[1];
    const int*   batch = (const int*)d_in[2];
    const float* W1    = (const float*)d_in[3];
    const float* b1    = (const float*)d_in[4];
    const float* W_out = (const float*)d_in[5];
    const float* b_out = (const float*)d_in[6];
    float* out = (float*)d_out;

    const int* src = edge;
    const int* dst = edge + N_EDGES;
    char* ws = (char*)d_ws;

    // workspace layout (bytes), total ~31.1 MB:
    int*   hist_g      = (int*)(ws);                  // 500*3128*4 = 6,256,000
    int*   tot_g       = (int*)(ws + 6256000);        // 3128*4
    int*   bucket_base = (int*)(ws + 6268544);        // 3129*4
    float* gsum        = (float*)(ws + 6281152);      // 512*20*4
    int*   offs_g      = (int*)(ws + 6322176);        // 800,000
    uint2* xh2         = (uint2*)(ws + 7122176);      // 8,000,000 (packed f16 rows, 40 B/node)
    int*   ebuf        = (int*)(ws + 15122176);       // 16,000,000

    k_hist<<<NC, 1024, 0, stream>>>(dst, hist_g, gsum);
    k_scan_col<<<NBP / 4, 512, 0, stream>>>(hist_g, tot_g);
    k_scan_tot<<<1, 1024, 0, stream>>>(tot_g, bucket_base);
    k_partition<<<NC, 1024, 0, stream>>>(src, dst, hist_g, bucket_base, ebuf);
    k_count_xh<<<NB, 256, 0, stream>>>(ebuf, bucket_base, (const float4*)x, offs_g, xh2);
    k_gather_fused<<<NB, 256, 0, stream>>>(ebuf, bucket_base, offs_g, xh2, batch, W1, b1, gsum);
    k_head<<<(N_GRAPHS + 63) / 64, 64, 0, stream>>>(gsum, batch, W_out, b_out, out);
}

// Round 13
// 153.228 us; speedup vs baseline: 1.3195x; 1.1365x over previous
//
#include <hip/hip_runtime.h>
#include <hip/hip_fp16.h>

#define N_NODES 200000
#define N_EDGES 4000000
#define N_GRAPHS 512
#define D 20
#define OUT 5

#define BSH 6            // final bucket: 64 nodes
#define BN 64
#define NFB 3125         // final buckets = ceil(200000/64)
#define NFBP 3136        // padded = 49*64
#define NBB 3129         // bucket_base live entries (>=3125 hold E)
#define NCB 49           // coarse buckets: dst>>12 (4096 nodes)
#define NC 500           // chunks for hist/partA
#define CHUNK 8000
#define CH2 7168         // partB chunk (within coarse segment)
#define NCH2 13          // 13*7168 = 93184 >= coarse max (+40 sigma)
#define MAX_EB 1792      // max edges per final bucket (mean 1280, +14 sigma)
#define GMAX 8

// ---------- P1: per-chunk FINAL-bucket histogram; block 0 zeros gsum & bucket_tot ----------
__launch_bounds__(1024)
__global__ void k_hist(const int* __restrict__ dst, int* __restrict__ hist_g,
                       float* __restrict__ gsum, int* __restrict__ bucket_tot) {
    __shared__ int h[NFBP];
    int t = threadIdx.x;
    if (blockIdx.x == 0) {
        for (int j = t; j < N_GRAPHS * D; j += 1024) gsum[j] = 0.f;
        for (int j = t; j < NFBP; j += 1024) bucket_tot[j] = 0;
    }
    for (int j = t; j < NFBP; j += 1024) h[j] = 0;
    __syncthreads();
    int base = blockIdx.x * CHUNK;
    for (int k = t; k < CHUNK; k += 1024) atomicAdd(&h[dst[base + k] >> BSH], 1);
    __syncthreads();
    for (int j = t; j < NFBP; j += 1024) hist_g[blockIdx.x * NFBP + j] = h[j];
}

// ---------- P2: column sums of hist matrix -> bucket_tot (row-coalesced, atomic reduce) ----------
__launch_bounds__(256)
__global__ void k_colsum(const int* __restrict__ hist_g, int* __restrict__ bucket_tot) {
    int col = blockIdx.x * 256 + threadIdx.x;          // 13 x-blocks * 256 = 3328 >= 3136
    if (col >= NFBP) return;
    int r0 = blockIdx.y * 50;                          // 10 y-blocks * 50 = 500 rows
    int sum = 0;
    for (int r = r0; r < r0 + 50; r++) sum += hist_g[r * NFBP + col];
    if (sum) atomicAdd(&bucket_tot[col], sum);
}

// ---------- P3: exclusive scan of bucket totals; init fcursor & coarse cursors ----------
__launch_bounds__(1024)
__global__ void k_scan_tot(const int* __restrict__ bucket_tot, int* __restrict__ bucket_base,
                           int* __restrict__ fcursor, int* __restrict__ ccursorA) {
    __shared__ int ps[1024];
    int t = threadIdx.x;
    int base = t * 4;                                  // 4096 >= NFBP
    int loc[4];
    int sum = 0;
    #pragma unroll
    for (int j = 0; j < 4; j++) {
        int idx = base + j;
        int x = (idx < NFBP) ? bucket_tot[idx] : 0;
        loc[j] = sum;
        sum += x;
    }
    ps[t] = sum;
    __syncthreads();
    for (int off = 1; off < 1024; off <<= 1) {
        int a = (t >= off) ? ps[t - off] : 0;
        __syncthreads();
        ps[t] += a;
        __syncthreads();
    }
    int carry = (t > 0) ? ps[t - 1] : 0;
    #pragma unroll
    for (int j = 0; j < 4; j++) {
        int idx = base + j;
        if (idx < NFBP) {
            int v = carry + loc[j];
            bucket_base[idx] = v;
            fcursor[idx] = v;
        }
    }
    __syncthreads();
    if (t < NCB) ccursorA[t] = bucket_base[t << 6];
}

// ---------- P4a: coarse partition (49 buckets), cursor-reserved, ~650B segments ----------
__launch_bounds__(1024)
__global__ void k_partA(const int* __restrict__ src, const int* __restrict__ dst,
                        int* __restrict__ ccursorA, int* __restrict__ ebufA) {
    __shared__ int h[NCB];
    __shared__ int lcur[NCB];
    int t = threadIdx.x, c = blockIdx.x;
    if (t < NCB) h[t] = 0;
    __syncthreads();
    int base = c * CHUNK;
    for (int k = t; k < CHUNK; k += 1024) atomicAdd(&h[dst[base + k] >> 12], 1);
    __syncthreads();
    if (t < NCB) lcur[t] = atomicAdd(&ccursorA[t], h[t]);   // global reserve
    __syncthreads();
    for (int k = t; k < CHUNK; k += 1024) {
        int d = dst[base + k];
        int sv = src[base + k];
        int cb = d >> 12;
        int pos = atomicAdd(&lcur[cb], 1);
        ebufA[pos] = (sv << 12) | (d & 4095);
    }
}

// ---------- P4b: fine partition within coarse (64 sub-buckets), ~450B segments ----------
__launch_bounds__(1024)
__global__ void k_partB(const int* __restrict__ ebufA, const int* __restrict__ bucket_base,
                        int* __restrict__ fcursor, int* __restrict__ ebuf) {
    int cb = blockIdx.x, j = blockIdx.y, t = threadIdx.x;
    int cbase = bucket_base[cb << 6];
    int cend_idx = (cb + 1) << 6; if (cend_idx > NFB) cend_idx = NFB;
    int cend = bucket_base[cend_idx];
    int lo = cbase + j * CH2;
    int hi = lo + CH2; if (hi > cend) hi = cend;
    if (lo >= hi) return;                              // uniform exit, pre-sync
    __shared__ int h[64];
    __shared__ int lcur[64];
    if (t < 64) h[t] = 0;
    __syncthreads();
    for (int k = lo + t; k < hi; k += 1024) atomicAdd(&h[(ebufA[k] >> 6) & 63], 1);
    __syncthreads();
    if (t < 64) lcur[t] = atomicAdd(&fcursor[(cb << 6) + t], h[t]);
    __syncthreads();
    for (int k = lo + t; k < hi; k += 1024) {
        int p = ebufA[k];
        int sb = (p >> 6) & 63;
        int pos = atomicAdd(&lcur[sb], 1);
        ebuf[pos] = ((p >> 12) << 6) | (p & 63);       // (src<<6)|dst_local
    }
}

// ---------- P5: per-bucket degree -> offs; xh = f16(dinv * x), packed 40B rows ----------
__launch_bounds__(256)
__global__ void k_count_xh(const int* __restrict__ ebuf, const int* __restrict__ bucket_base,
                           const float4* __restrict__ x4, int* __restrict__ offs_g,
                           uint2* __restrict__ xh2) {
    __shared__ int cnt[BN];
    __shared__ int s[BN];
    __shared__ float sdi[BN];
    int b = blockIdx.x, t = threadIdx.x;
    int eb = bucket_base[b], ee = bucket_base[b + 1];
    if (t < BN) cnt[t] = 0;
    __syncthreads();
    for (int k = eb + t; k < ee; k += 256) atomicAdd(&cnt[ebuf[k] & (BN - 1)], 1);
    __syncthreads();
    int nbn = N_NODES - (b << BSH); if (nbn > BN) nbn = BN;
    int v = (t < BN) ? cnt[t] : 0;
    if (t < BN) s[t] = v;
    __syncthreads();
    for (int off = 1; off < BN; off <<= 1) {
        int a = 0;
        if (t < BN && t >= off) a = s[t - off];
        __syncthreads();
        if (t < BN) s[t] += a;
        __syncthreads();
    }
    if (t < nbn) {
        int node = (b << BSH) + t;
        offs_g[node] = eb + s[t] - v;
        sdi[t] = rsqrtf((float)(v + 1));
    }
    __syncthreads();
    int nw = nbn * 5;
    for (int j = t; j < nw; j += 256) {
        int vl = j / 5, q = j - vl * 5;
        int node = (b << BSH) + vl;
        float4 xv = x4[node * 5 + q];
        float di = sdi[vl];
        __half2 h0 = __float22half2_rn(make_float2(xv.x * di, xv.y * di));
        __half2 h1 = __float22half2_rn(make_float2(xv.z * di, xv.w * di));
        uint2 u;
        u.x = *(unsigned int*)&h0;
        u.y = *(unsigned int*)&h1;
        xh2[node * 5 + q] = u;
    }
}

// ---------- P6: node-parallel gather (8x unrolled MLP) + W1 matvec + relu + pool ----------
__launch_bounds__(256, 8)
__global__ void k_gather_fused(const int* __restrict__ ebuf, const int* __restrict__ bucket_base,
                               const int* __restrict__ offs_g, const uint2* __restrict__ xh2,
                               const int* __restrict__ batch, const float* __restrict__ W1,
                               const float* __restrict__ b1, float* __restrict__ gsum) {
    __shared__ int loff[BN + 1];
    __shared__ int cur[BN];
    __shared__ int lcsr[MAX_EB];
    __shared__ float w[D * D];
    __shared__ float wb[D];
    __shared__ float sagg[BN][21];
    __shared__ float lgsum[GMAX][D];
    int b = blockIdx.x, t = threadIdx.x;
    int eb = bucket_base[b], ee = bucket_base[b + 1];
    int n = ee - eb;
    int nbn = N_NODES - (b << BSH); if (nbn > BN) nbn = BN;

    for (int j = t; j < D * D; j += 256) w[j] = W1[j];
    if (t < D) wb[t] = b1[t];
    if (t < GMAX * D) ((float*)lgsum)[t] = 0.f;
    if (t < nbn) {
        int o = offs_g[(b << BSH) + t] - eb;
        loff[t] = o;
        cur[t] = o;
    }
    if (t == 0) loff[nbn] = n;
    __syncthreads();

    for (int k = t; k < n; k += 256) {
        int p = ebuf[eb + k];
        int pos = atomicAdd(&cur[p & (BN - 1)], 1);
        if (pos < MAX_EB) lcsr[pos] = p >> BSH;
    }
    __syncthreads();

    int nw = nbn * 5;
    for (int j = t; j < nw; j += 256) {
        int vl = j / 5, q = j - vl * 5;
        int node = (b << BSH) + vl;
        uint2 u = xh2[node * 5 + q];
        float2 a0 = __half22float2(*(__half2*)&u.x);
        float2 a1 = __half22float2(*(__half2*)&u.y);
        float accx = a0.x, accy = a0.y, accz = a1.x, accw = a1.y;
        float bccx = 0.f, bccy = 0.f, bccz = 0.f, bccw = 0.f;
        int lo = loff[vl], hi = loff[vl + 1];
        if (hi > MAX_EB) hi = MAX_EB;
        if (lo > MAX_EB) lo = MAX_EB;
        int k = lo;
        for (; k + 8 <= hi; k += 8) {
            int s0 = lcsr[k],     s1 = lcsr[k + 1], s2 = lcsr[k + 2], s3 = lcsr[k + 3];
            int s4 = lcsr[k + 4], s5 = lcsr[k + 5], s6 = lcsr[k + 6], s7 = lcsr[k + 7];
            uint2 m0 = xh2[s0 * 5 + q];
            uint2 m1 = xh2[s1 * 5 + q];
            uint2 m2 = xh2[s2 * 5 + q];
            uint2 m3 = xh2[s3 * 5 + q];
            uint2 m4 = xh2[s4 * 5 + q];
            uint2 m5 = xh2[s5 * 5 + q];
            uint2 m6 = xh2[s6 * 5 + q];
            uint2 m7 = xh2[s7 * 5 + q];
            float2 p0 = __half22float2(*(__half2*)&m0.x);
            float2 p1 = __half22float2(*(__half2*)&m0.y);
            float2 q0 = __half22float2(*(__half2*)&m1.x);
            float2 q1 = __half22float2(*(__half2*)&m1.y);
            float2 r0 = __half22float2(*(__half2*)&m2.x);
            float2 r1 = __half22float2(*(__half2*)&m2.y);
            float2 t0 = __half22float2(*(__half2*)&m3.x);
            float2 t1 = __half22float2(*(__half2*)&m3.y);
            accx += p0.x + q0.x; accy += p0.y + q0.y;
            accz += p1.x + q1.x; accw += p1.y + q1.y;
            bccx += r0.x + t0.x; bccy += r0.y + t0.y;
            bccz += r1.x + t1.x; bccw += r1.y + t1.y;
            float2 p2 = __half22float2(*(__half2*)&m4.x);
            float2 p3 = __half22float2(*(__half2*)&m4.y);
            float2 q2 = __half22float2(*(__half2*)&m5.x);
            float2 q3 = __half22float2(*(__half2*)&m5.y);
            float2 r2 = __half22float2(*(__half2*)&m6.x);
            float2 r3 = __half22float2(*(__half2*)&m6.y);
            float2 t2 = __half22float2(*(__half2*)&m7.x);
            float2 t3 = __half22float2(*(__half2*)&m7.y);
            accx += p2.x + q2.x; accy += p2.y + q2.y;
            accz += p3.x + q3.x; accw += p3.y + q3.y;
            bccx += r2.x + t2.x; bccy += r2.y + t2.y;
            bccz += r3.x + t3.x; bccw += r3.y + t3.y;
        }
        for (; k + 4 <= hi; k += 4) {
            int s0 = lcsr[k], s1 = lcsr[k + 1], s2 = lcsr[k + 2], s3 = lcsr[k + 3];
            uint2 m0 = xh2[s0 * 5 + q];
            uint2 m1 = xh2[s1 * 5 + q];
            uint2 m2 = xh2[s2 * 5 + q];
            uint2 m3 = xh2[s3 * 5 + q];
            float2 p0 = __half22float2(*(__half2*)&m0.x);
            float2 p1 = __half22float2(*(__half2*)&m0.y);
            float2 q0 = __half22float2(*(__half2*)&m1.x);
            float2 q1 = __half22float2(*(__half2*)&m1.y);
            float2 r0 = __half22float2(*(__half2*)&m2.x);
            float2 r1 = __half22float2(*(__half2*)&m2.y);
            float2 t0 = __half22float2(*(__half2*)&m3.x);
            float2 t1 = __half22float2(*(__half2*)&m3.y);
            accx += p0.x + q0.x; accy += p0.y + q0.y;
            accz += p1.x + q1.x; accw += p1.y + q1.y;
            bccx += r0.x + t0.x; bccy += r0.y + t0.y;
            bccz += r1.x + t1.x; bccw += r1.y + t1.y;
        }
        for (; k < hi; k++) {
            int sv = lcsr[k];
            uint2 m = xh2[sv * 5 + q];
            float2 m0 = __half22float2(*(__half2*)&m.x);
            float2 m1 = __half22float2(*(__half2*)&m.y);
            accx += m0.x; accy += m0.y; accz += m1.x; accw += m1.y;
        }
        sagg[vl][q * 4 + 0] = accx + bccx;
        sagg[vl][q * 4 + 1] = accy + bccy;
        sagg[vl][q * 4 + 2] = accz + bccz;
        sagg[vl][q * 4 + 3] = accw + bccw;
    }
    __syncthreads();

    int g0 = batch[b << BSH];
    int glast = batch[(b << BSH) + nbn - 1];
    int gcnt = glast - g0 + 1;

    if (t < nbn) {
        int node = (b << BSH) + t;
        float di = rsqrtf((float)(loff[t + 1] - loff[t] + 1));
        int gi = batch[node] - g0;
        float pre[D];
        #pragma unroll
        for (int d = 0; d < D; d++) pre[d] = sagg[t][d];
        int t20 = t % D;
        bool fits = (gcnt <= GMAX);
        for (int jj = 0; jj < D; jj++) {
            int o = t20 + jj; if (o >= D) o -= D;
            float h = 0.f;
            #pragma unroll
            for (int d = 0; d < D; d++) h = fmaf(pre[d], w[d * D + o], h);
            h = fmaf(h, di, wb[o]);
            h = fmaxf(h, 0.f);
            if (fits) atomicAdd(&lgsum[gi][o], h);
            else atomicAdd(&gsum[(g0 + gi) * D + o], h);  // safety path
        }
    }
    __syncthreads();
    if (gcnt <= GMAX && t < gcnt * D) {
        atomicAdd(&gsum[(g0 + t / D) * D + (t % D)], lgsum[t / D][t % D]);
    }
}

// ---------- P7: head: mean -> W_out -> softmax ----------
__launch_bounds__(64)
__global__ void k_head(const float* __restrict__ gsum, const int* __restrict__ batch,
                       const float* __restrict__ W_out, const float* __restrict__ b_out,
                       float* __restrict__ out) {
    __shared__ float wo[D * OUT];
    __shared__ float bo[OUT];
    int t = threadIdx.x;
    for (int j = t; j < D * OUT; j += 64) wo[j] = W_out[j];
    if (t < OUT) bo[t] = b_out[t];
    __syncthreads();
    int g = blockIdx.x * 64 + t;
    if (g >= N_GRAPHS) return;
    auto lb = [&](int key) {
        int lo = 0, hi = N_NODES;
        while (lo < hi) { int mid = (lo + hi) >> 1; if (batch[mid] < key) lo = mid + 1; else hi = mid; }
        return lo;
    };
    int cnt = lb(g + 1) - lb(g);
    float inv = 1.0f / fmaxf((float)cnt, 1.0f);
    float logits[OUT];
    #pragma unroll
    for (int o = 0; o < OUT; o++) logits[o] = bo[o];
    #pragma unroll
    for (int d = 0; d < D; d++) {
        float p = gsum[g * D + d] * inv;
        #pragma unroll
        for (int o = 0; o < OUT; o++) logits[o] = fmaf(p, wo[d * OUT + o], logits[o]);
    }
    float m = logits[0];
    #pragma unroll
    for (int o = 1; o < OUT; o++) m = fmaxf(m, logits[o]);
    float ex[OUT], sum = 0.f;
    #pragma unroll
    for (int o = 0; o < OUT; o++) { ex[o] = __expf(logits[o] - m); sum += ex[o]; }
    float isum = 1.0f / sum;
    #pragma unroll
    for (int o = 0; o < OUT; o++) out[g * OUT + o] = ex[o] * isum;
}

extern "C" void kernel_launch(void* const* d_in, const int* in_sizes, int n_in,
                              void* d_out, int out_size, void* d_ws, size_t ws_size,
                              hipStream_t stream) {
    const float* x     = (const float*)d_in[0];
    const int*   edge  = (const int*)d_in[1];
    const int*   batch = (const int*)d_in[2];
    const float* W1    = (const float*)d_in[3];
    const float* b1    = (const float*)d_in[4];
    const float* W_out = (const float*)d_in[5];
    const float* b_out = (const float*)d_in[6];
    float* out = (float*)d_out;

    const int* src = edge;
    const int* dst = edge + N_EDGES;
    char* ws = (char*)d_ws;

    // workspace layout (bytes), total ~47.2 MB (ws >= 50.4 MB proven in R3):
    int*   hist_g      = (int*)(ws);                  // 500*3136*4 = 6,272,000
    int*   bucket_tot  = (int*)(ws + 6272000);        // 3136*4
    int*   bucket_base = (int*)(ws + 6284544);        // 3136*4
    int*   fcursor     = (int*)(ws + 6297088);        // 3136*4
    int*   ccursorA    = (int*)(ws + 6309632);        // 64*4
    float* gsum        = (float*)(ws + 6309888);      // 512*20*4
    int*   offs_g      = (int*)(ws + 6350848);        // 800,000
    uint2* xh2         = (uint2*)(ws + 7150848);      // 8,000,000
    int*   ebufA       = (int*)(ws + 15150848);       // 16,000,000
    int*   ebuf        = (int*)(ws + 31150848);       // 16,000,000

    k_hist<<<NC, 1024, 0, stream>>>(dst, hist_g, gsum, bucket_tot);
    k_colsum<<<dim3(13, 10), 256, 0, stream>>>(hist_g, bucket_tot);
    k_scan_tot<<<1, 1024, 0, stream>>>(bucket_tot, bucket_base, fcursor, ccursorA);
    k_partA<<<NC, 1024, 0, stream>>>(src, dst, ccursorA, ebufA);
    k_partB<<<dim3(NCB, NCH2), 1024, 0, stream>>>(ebufA, bucket_base, fcursor, ebuf);
    k_count_xh<<<NFB, 256, 0, stream>>>(ebuf, bucket_base, (const float4*)x, offs_g, xh2);
    k_gather_fused<<<NFB, 256, 0, stream>>>(ebuf, bucket_base, offs_g, xh2, batch, W1, b1, gsum);
    k_head<<<(N_GRAPHS + 63) / 64, 64, 0, stream>>>(gsum, batch, W_out, b_out, out);
}